// Round 1
// baseline (650.633 us; speedup 1.0000x reference)
//
#include <hip/hip_runtime.h>

typedef __bf16 bf16x8 __attribute__((ext_vector_type(8)));
typedef float f32x4 __attribute__((ext_vector_type(4)));

#define LOG2E 1.44269504088896340736f

static __device__ __forceinline__ unsigned short f2bf(float f) {
    unsigned int u = __builtin_bit_cast(unsigned int, f);
    u += 0x7fffu + ((u >> 16) & 1u);   // RNE
    return (unsigned short)(u >> 16);
}

// ---------------- fp32 -> bf16 convert ----------------
__global__ void cvt_kernel(const float* __restrict__ in, unsigned short* __restrict__ out, int n4) {
    int i = blockIdx.x * blockDim.x + threadIdx.x;
    int stride = gridDim.x * blockDim.x;
    for (; i < n4; i += stride) {
        float4 v = reinterpret_cast<const float4*>(in)[i];
        ushort4 o;
        o.x = f2bf(v.x); o.y = f2bf(v.y); o.z = f2bf(v.z); o.w = f2bf(v.w);
        reinterpret_cast<ushort4*>(out)[i] = o;
    }
}

// ---------------- bf16 GEMM, C = A * B^T (+bias) ----------------
// A: [M][K] bf16 row-major, B: [N][K] bf16 row-major. 128x128 tile, BK=64,
// 4 waves (2x2), each wave 64x64 via 4x4 frags of 16x16x32 MFMA.
// LDS double-buffered; staged with global_load_lds width 16; XOR-swizzle
// (chunk ^= row&7) applied by pre-swizzling the GLOBAL source (linear LDS
// dest) and swizzling the ds_read address (rule #21 both-sides).
// MODE 0: scatter-write bf16 QKV (Q scaled 0.125, V transposed per head).
// MODE 1: fp32 C with bias.
template <int MODE>
__global__ __launch_bounds__(256, 2) void gemm_bt(const unsigned short* __restrict__ A,
                                                  const unsigned short* __restrict__ B,
                                                  const float* __restrict__ bias,
                                                  void* __restrict__ Cout,
                                                  int M, int N, int K) {
    __shared__ unsigned short As[2][128 * 64];
    __shared__ unsigned short Bs[2][128 * 64];
    const int tid = threadIdx.x;
    const int w = tid >> 6, lane = tid & 63;
    const int wr = w >> 1, wc = w & 1;
    const int bm0 = blockIdx.y << 7, bn0 = blockIdx.x << 7;
    const int l15 = lane & 15, l4 = lane >> 4;

    const int srow = w * 8 + (lane >> 3);            // staging row within 32-row slab
    const int gch = (lane & 7) ^ (lane >> 3);        // pre-swizzled source chunk

    f32x4 acc[4][4] = {};

    auto stage = [&](int buf, int kt) {
        const int k0 = kt << 6;
        #pragma unroll
        for (int i = 0; i < 4; ++i) {
            int row = i * 32 + srow;
            const unsigned short* ga = A + (size_t)(bm0 + row) * K + k0 + gch * 8;
            __builtin_amdgcn_global_load_lds(
                (const __attribute__((address_space(1))) void*)ga,
                (__attribute__((address_space(3))) void*)&As[buf][i * 2048 + w * 512],
                16, 0, 0);
            const unsigned short* gb = B + (size_t)(bn0 + row) * K + k0 + gch * 8;
            __builtin_amdgcn_global_load_lds(
                (const __attribute__((address_space(1))) void*)gb,
                (__attribute__((address_space(3))) void*)&Bs[buf][i * 2048 + w * 512],
                16, 0, 0);
        }
    };

    const int nk = K >> 6;
    stage(0, 0);
    __syncthreads();
    int buf = 0;
    for (int kt = 0; kt < nk; ++kt) {
        if (kt + 1 < nk) stage(buf ^ 1, kt + 1);
        const unsigned short* as = &As[buf][0];
        const unsigned short* bs = &Bs[buf][0];
        #pragma unroll
        for (int s = 0; s < 2; ++s) {
            bf16x8 af[4], bfr[4];
            #pragma unroll
            for (int t = 0; t < 4; ++t) {
                int rowa = wr * 64 + t * 16 + l15;
                int cha = (s * 4 + l4) ^ (rowa & 7);
                af[t] = *(const bf16x8*)&as[rowa * 64 + cha * 8];
                int rowb = wc * 64 + t * 16 + l15;
                int chb = (s * 4 + l4) ^ (rowb & 7);
                bfr[t] = *(const bf16x8*)&bs[rowb * 64 + chb * 8];
            }
            #pragma unroll
            for (int i = 0; i < 4; ++i)
                #pragma unroll
                for (int j = 0; j < 4; ++j)
                    acc[i][j] = __builtin_amdgcn_mfma_f32_16x16x32_bf16(af[i], bfr[j], acc[i][j], 0, 0, 0);
        }
        __syncthreads();
        buf ^= 1;
    }

    if (MODE == 0) {
        // QKV scatter: col in [0,3072): which=col>>10, h=(col>>6)&15, d=col&63
        // Q/K: [(bh)*2048 + n]*64 + d ; V transposed: [(bh)*64 + d]*2048 + n
        unsigned short* O = (unsigned short*)Cout;
        #pragma unroll
        for (int j = 0; j < 4; ++j) {
            int col = bn0 + wc * 64 + j * 16 + l15;
            float bv = bias[col];
            int which = col >> 10;
            int h = (col >> 6) & 15;
            int d = col & 63;
            #pragma unroll
            for (int i = 0; i < 4; ++i) {
                #pragma unroll
                for (int r = 0; r < 4; ++r) {
                    int row = bm0 + wr * 64 + i * 16 + l4 * 4 + r;
                    int b = row >> 11, n = row & 2047;
                    float v = acc[i][j][r] + bv;
                    size_t idx;
                    if (which == 0) { v *= 0.125f; idx = ((size_t)((b * 16 + h) * 2048 + n)) * 64 + d; }
                    else if (which == 1) { idx = (size_t)8388608 + ((size_t)((b * 16 + h) * 2048 + n)) * 64 + d; }
                    else { idx = (size_t)16777216 + ((size_t)((b * 16 + h) * 64 + d)) * 2048 + n; }
                    O[idx] = f2bf(v);
                }
            }
        }
    } else {
        float* C = (float*)Cout;
        #pragma unroll
        for (int j = 0; j < 4; ++j) {
            int col = bn0 + wc * 64 + j * 16 + l15;
            float bv = bias[col];
            #pragma unroll
            for (int i = 0; i < 4; ++i) {
                #pragma unroll
                for (int r = 0; r < 4; ++r) {
                    int row = bm0 + wr * 64 + i * 16 + l4 * 4 + r;
                    C[(size_t)row * N + col] = acc[i][j][r] + bv;
                }
            }
        }
    }
}

// ---------------- flash attention ----------------
// qkv: Q[64 heads][2048][64], K same, V transposed [64 heads][64][2048], bf16.
// Q pre-scaled by 0.125. Block = 4 waves; wave handles 16 Q-rows; KBLK=128.
// K/V frags read straight from global (256 KB/head -> L1/L2 resident).
// P relayout (C-layout -> A-layout) via per-wave XOR-swizzled LDS buffer.
__global__ __launch_bounds__(256) void attn_kernel(const unsigned short* __restrict__ qkv,
                                                   unsigned short* __restrict__ out) {
    const int tid = threadIdx.x;
    const int w = tid >> 6, lane = tid & 63;
    const int l15 = lane & 15, l4 = lane >> 4;
    const int qt = blockIdx.x;   // 0..31
    const int bh = blockIdx.y;   // 0..63
    const size_t SEC = 8388608;

    const unsigned short* Q  = qkv + (size_t)bh * (2048 * 64);
    const unsigned short* Kp = qkv + SEC + (size_t)bh * (2048 * 64);
    const unsigned short* Vt = qkv + 2 * SEC + (size_t)bh * (64 * 2048);

    const int q0 = qt * 64 + w * 16;

    bf16x8 aq0 = *(const bf16x8*)&Q[(size_t)(q0 + l15) * 64 + l4 * 8];
    bf16x8 aq1 = *(const bf16x8*)&Q[(size_t)(q0 + l15) * 64 + 32 + l4 * 8];

    f32x4 o[4] = {};
    float m[4] = {-1e30f, -1e30f, -1e30f, -1e30f};
    float lsum[4] = {0.f, 0.f, 0.f, 0.f};

    __shared__ __attribute__((aligned(16))) unsigned char plds[4][4096];
    unsigned char* mp = plds[w];

    for (int kb = 0; kb < 2048; kb += 128) {
        f32x4 s[8];
        #pragma unroll
        for (int ct = 0; ct < 8; ++ct) {
            const unsigned short* kr = Kp + (size_t)(kb + ct * 16 + l15) * 64 + l4 * 8;
            bf16x8 b0 = *(const bf16x8*)kr;
            bf16x8 b1 = *(const bf16x8*)(kr + 32);
            f32x4 z = {0.f, 0.f, 0.f, 0.f};
            z = __builtin_amdgcn_mfma_f32_16x16x32_bf16(aq0, b0, z, 0, 0, 0);
            s[ct] = __builtin_amdgcn_mfma_f32_16x16x32_bf16(aq1, b1, z, 0, 0, 0);
        }
        // online softmax; row j lives in lanes sharing l4, spread over 16 low lanes
        float corr[4];
        #pragma unroll
        for (int j = 0; j < 4; ++j) {
            float mx = s[0][j];
            #pragma unroll
            for (int ct = 1; ct < 8; ++ct) mx = fmaxf(mx, s[ct][j]);
            mx = fmaxf(mx, __shfl_xor(mx, 1));
            mx = fmaxf(mx, __shfl_xor(mx, 2));
            mx = fmaxf(mx, __shfl_xor(mx, 4));
            mx = fmaxf(mx, __shfl_xor(mx, 8));
            float mn = fmaxf(m[j], mx);
            corr[j] = exp2f((m[j] - mn) * LOG2E);
            m[j] = mn;
            float rs = 0.f;
            #pragma unroll
            for (int ct = 0; ct < 8; ++ct) {
                float p = exp2f((s[ct][j] - mn) * LOG2E);
                s[ct][j] = p;
                rs += p;
            }
            rs += __shfl_xor(rs, 1);
            rs += __shfl_xor(rs, 2);
            rs += __shfl_xor(rs, 4);
            rs += __shfl_xor(rs, 8);
            lsum[j] = lsum[j] * corr[j] + rs;
        }
        #pragma unroll
        for (int co = 0; co < 4; ++co)
            #pragma unroll
            for (int j = 0; j < 4; ++j) o[co][j] *= corr[j];

        asm volatile("" ::: "memory");  // fence: no P-read hoisted above writes (TBAA)
        // write P: element (row=l4*4+j, col=ct*16+l15), swizzle chunk ^= row&7
        #pragma unroll
        for (int ct = 0; ct < 8; ++ct) {
            int colh = ct * 2 + (l15 >> 3);
            int cb = (l15 & 7) * 2;
            #pragma unroll
            for (int j = 0; j < 4; ++j) {
                int row = l4 * 4 + j;
                *(unsigned short*)(mp + row * 256 + ((colh ^ (row & 7)) << 4) + cb) = f2bf(s[ct][j]);
            }
        }
        asm volatile("" ::: "memory");  // fence: reads stay after writes
        // PV: A = P from LDS (row=l15, chunk=(ks*4+l4)^(row&7)); B = Vt contiguous
        #pragma unroll
        for (int ks = 0; ks < 4; ++ks) {
            int chp = (ks * 4 + l4) ^ (l15 & 7);
            bf16x8 pa = *(const bf16x8*)(mp + l15 * 256 + chp * 16);
            #pragma unroll
            for (int co = 0; co < 4; ++co) {
                const unsigned short* vr = Vt + (size_t)(co * 16 + l15) * 2048 + kb + ks * 32 + l4 * 8;
                bf16x8 bv = *(const bf16x8*)vr;
                o[co] = __builtin_amdgcn_mfma_f32_16x16x32_bf16(pa, bv, o[co], 0, 0, 0);
            }
        }
        asm volatile("" ::: "memory");  // fence: next-iter writes stay after reads
    }

    const int b = bh >> 4, h = bh & 15;
    #pragma unroll
    for (int j = 0; j < 4; ++j) {
        float r = 1.0f / lsum[j];
        int n = q0 + l4 * 4 + j;
        size_t base = ((size_t)(b * 2048 + n)) * 1024 + h * 64;
        #pragma unroll
        for (int co = 0; co < 4; ++co)
            out[base + co * 16 + l15] = f2bf(o[co][j] * r);
    }
}

// ---------------- launch ----------------
extern "C" void kernel_launch(void* const* d_in, const int* in_sizes, int n_in,
                              void* d_out, int out_size, void* d_ws, size_t ws_size,
                              hipStream_t stream) {
    (void)in_sizes; (void)n_in; (void)out_size; (void)ws_size;
    const float* x     = (const float*)d_in[0];
    const float* w_qkv = (const float*)d_in[1];
    const float* b_qkv = (const float*)d_in[2];
    const float* w_out = (const float*)d_in[3];
    const float* b_out = (const float*)d_in[4];

    unsigned short* ws = (unsigned short*)d_ws;
    // workspace map (ushort elems): xb/attn_out 8388608 | wqkvb 3145728 |
    // woutb 1048576 | qkvb 25165824  => 75.5 MB total
    unsigned short* xb    = ws;
    unsigned short* wqkvb = ws + 8388608;
    unsigned short* woutb = ws + 11534336;
    unsigned short* qkvb  = ws + 12582912;

    cvt_kernel<<<dim3(2048), dim3(256), 0, stream>>>(x, xb, 8388608 / 4);
    cvt_kernel<<<dim3(1024), dim3(256), 0, stream>>>(w_qkv, wqkvb, 3145728 / 4);
    cvt_kernel<<<dim3(512),  dim3(256), 0, stream>>>(w_out, woutb, 1048576 / 4);

    gemm_bt<0><<<dim3(24, 64), dim3(256), 0, stream>>>(xb, wqkvb, b_qkv, (void*)qkvb, 8192, 3072, 1024);

    // attn overwrites xb (x is dead after the QKV GEMM)
    attn_kernel<<<dim3(32, 64), dim3(256), 0, stream>>>(qkvb, xb);

    gemm_bt<1><<<dim3(8, 64), dim3(256), 0, stream>>>(xb, woutb, b_out, d_out, 8192, 1024, 1024);
}

// Round 2
// 370.939 us; speedup vs baseline: 1.7540x; 1.7540x over previous
//
#include <hip/hip_runtime.h>

typedef __bf16 bf16x8 __attribute__((ext_vector_type(8)));
typedef float f32x4 __attribute__((ext_vector_type(4)));
typedef float f32x16 __attribute__((ext_vector_type(16)));

#define LOG2E 1.44269504088896340736f

static __device__ __forceinline__ unsigned short f2bf(float f) {
    unsigned int u = __builtin_bit_cast(unsigned int, f);
    u += 0x7fffu + ((u >> 16) & 1u);   // RNE
    return (unsigned short)(u >> 16);
}

// ---------------- fp32 -> bf16 convert ----------------
__global__ void cvt_kernel(const float* __restrict__ in, unsigned short* __restrict__ out, int n4) {
    int i = blockIdx.x * blockDim.x + threadIdx.x;
    int stride = gridDim.x * blockDim.x;
    for (; i < n4; i += stride) {
        float4 v = reinterpret_cast<const float4*>(in)[i];
        ushort4 o;
        o.x = f2bf(v.x); o.y = f2bf(v.y); o.z = f2bf(v.z); o.w = f2bf(v.w);
        reinterpret_cast<ushort4*>(out)[i] = o;
    }
}

// ---------------- bf16 GEMM, C = A * B^T (+bias) ----------------
// (unchanged from round 1 — passing; revisit after attention)
template <int MODE>
__global__ __launch_bounds__(256, 2) void gemm_bt(const unsigned short* __restrict__ A,
                                                  const unsigned short* __restrict__ B,
                                                  const float* __restrict__ bias,
                                                  void* __restrict__ Cout,
                                                  int M, int N, int K) {
    __shared__ unsigned short As[2][128 * 64];
    __shared__ unsigned short Bs[2][128 * 64];
    const int tid = threadIdx.x;
    const int w = tid >> 6, lane = tid & 63;
    const int wr = w >> 1, wc = w & 1;
    const int bm0 = blockIdx.y << 7, bn0 = blockIdx.x << 7;
    const int l15 = lane & 15, l4 = lane >> 4;

    const int srow = w * 8 + (lane >> 3);
    const int gch = (lane & 7) ^ (lane >> 3);

    f32x4 acc[4][4] = {};

    auto stage = [&](int buf, int kt) {
        const int k0 = kt << 6;
        #pragma unroll
        for (int i = 0; i < 4; ++i) {
            int row = i * 32 + srow;
            const unsigned short* ga = A + (size_t)(bm0 + row) * K + k0 + gch * 8;
            __builtin_amdgcn_global_load_lds(
                (const __attribute__((address_space(1))) void*)ga,
                (__attribute__((address_space(3))) void*)&As[buf][i * 2048 + w * 512],
                16, 0, 0);
            const unsigned short* gb = B + (size_t)(bn0 + row) * K + k0 + gch * 8;
            __builtin_amdgcn_global_load_lds(
                (const __attribute__((address_space(1))) void*)gb,
                (__attribute__((address_space(3))) void*)&Bs[buf][i * 2048 + w * 512],
                16, 0, 0);
        }
    };

    const int nk = K >> 6;
    stage(0, 0);
    __syncthreads();
    int buf = 0;
    for (int kt = 0; kt < nk; ++kt) {
        if (kt + 1 < nk) stage(buf ^ 1, kt + 1);
        const unsigned short* as = &As[buf][0];
        const unsigned short* bs = &Bs[buf][0];
        #pragma unroll
        for (int s = 0; s < 2; ++s) {
            bf16x8 af[4], bfr[4];
            #pragma unroll
            for (int t = 0; t < 4; ++t) {
                int rowa = wr * 64 + t * 16 + l15;
                int cha = (s * 4 + l4) ^ (rowa & 7);
                af[t] = *(const bf16x8*)&as[rowa * 64 + cha * 8];
                int rowb = wc * 64 + t * 16 + l15;
                int chb = (s * 4 + l4) ^ (rowb & 7);
                bfr[t] = *(const bf16x8*)&bs[rowb * 64 + chb * 8];
            }
            #pragma unroll
            for (int i = 0; i < 4; ++i)
                #pragma unroll
                for (int j = 0; j < 4; ++j)
                    acc[i][j] = __builtin_amdgcn_mfma_f32_16x16x32_bf16(af[i], bfr[j], acc[i][j], 0, 0, 0);
        }
        __syncthreads();
        buf ^= 1;
    }

    if (MODE == 0) {
        unsigned short* O = (unsigned short*)Cout;
        #pragma unroll
        for (int j = 0; j < 4; ++j) {
            int col = bn0 + wc * 64 + j * 16 + l15;
            float bv = bias[col];
            int which = col >> 10;
            int h = (col >> 6) & 15;
            int d = col & 63;
            #pragma unroll
            for (int i = 0; i < 4; ++i) {
                #pragma unroll
                for (int r = 0; r < 4; ++r) {
                    int row = bm0 + wr * 64 + i * 16 + l4 * 4 + r;
                    int b = row >> 11, n = row & 2047;
                    float v = acc[i][j][r] + bv;
                    size_t idx;
                    if (which == 0) { v *= 0.125f; idx = ((size_t)((b * 16 + h) * 2048 + n)) * 64 + d; }
                    else if (which == 1) { idx = (size_t)8388608 + ((size_t)((b * 16 + h) * 2048 + n)) * 64 + d; }
                    else { idx = (size_t)16777216 + ((size_t)((b * 16 + h) * 64 + d)) * 2048 + n; }
                    O[idx] = f2bf(v);
                }
            }
        }
    } else {
        float* C = (float*)Cout;
        #pragma unroll
        for (int j = 0; j < 4; ++j) {
            int col = bn0 + wc * 64 + j * 16 + l15;
            float bv = bias[col];
            #pragma unroll
            for (int i = 0; i < 4; ++i) {
                #pragma unroll
                for (int r = 0; r < 4; ++r) {
                    int row = bm0 + wr * 64 + i * 16 + l4 * 4 + r;
                    C[(size_t)row * N + col] = acc[i][j][r] + bv;
                }
            }
        }
    }
}

// ---------------- flash attention v2: swapped-operand 32x32, LDS-free ----------------
// qkv: Q[64 bh][2048][64] (pre-scaled 0.125), K[64 bh][2048][64], Vt[64 bh][64][2048], bf16.
// Wave owns 32 q rows. S^T = mfma_32x32x16(A=K, B=Q): lane column = q = lane&31,
// 16 k-values in regs (k = (r&3)+8*(r>>2)+4*hi). Row softmax = in-lane + 1 shfl_xor(32).
// O^T = mfma(A=Vt, B=P^T): column = q again -> rescale/norm factors lane-local.
// P relayout C->B via v_cvt_pk_bf16_f32 + shfl_xor(32) (T12). Defer-max THR=8 (T13).
__global__ __launch_bounds__(256, 3) void attn_kernel(const unsigned short* __restrict__ qkv,
                                                      unsigned short* __restrict__ out) {
    const int tid = threadIdx.x;
    const int w = tid >> 6, lane = tid & 63;
    const int ql = lane & 31;        // q (and k-row / d-row) lane index
    const int hi = lane >> 5;
    const int qt = blockIdx.x;       // 0..15 (128 q rows per block)
    const int bh = blockIdx.y;       // 0..63
    const size_t SEC = 8388608;

    const unsigned short* Q  = qkv + (size_t)bh * (2048 * 64);
    const unsigned short* Kp = qkv + SEC + (size_t)bh * (2048 * 64);
    const unsigned short* Vt = qkv + 2 * SEC + (size_t)bh * (64 * 2048);

    const int q0 = qt * 128 + w * 32;

    // Q as B-operand: lane holds q=ql, d = c*16 + hi*8 + 0..7 (contiguous)
    bf16x8 qb[4];
    #pragma unroll
    for (int c = 0; c < 4; ++c)
        qb[c] = *(const bf16x8*)&Q[(size_t)(q0 + ql) * 64 + c * 16 + hi * 8];

    f32x16 o0 = {}, o1 = {};     // O^T tiles: d 0-31 / 32-63 rows, q cols
    float m = -1e30f, lsum = 0.f;

    for (int kb = 0; kb < 2048; kb += 32) {
        // K as A-operand: lane holds k-row = kb+ql, d = c*16 + hi*8 + 0..7
        const unsigned short* kp = Kp + (size_t)(kb + ql) * 64 + hi * 8;
        bf16x8 ka0 = *(const bf16x8*)(kp);
        bf16x8 ka1 = *(const bf16x8*)(kp + 16);
        bf16x8 ka2 = *(const bf16x8*)(kp + 32);
        bf16x8 ka3 = *(const bf16x8*)(kp + 48);

        f32x16 s = {};
        s = __builtin_amdgcn_mfma_f32_32x32x16_bf16(ka0, qb[0], s, 0, 0, 0);
        s = __builtin_amdgcn_mfma_f32_32x32x16_bf16(ka1, qb[1], s, 0, 0, 0);
        s = __builtin_amdgcn_mfma_f32_32x32x16_bf16(ka2, qb[2], s, 0, 0, 0);
        s = __builtin_amdgcn_mfma_f32_32x32x16_bf16(ka3, qb[3], s, 0, 0, 0);

        // Vt as A-operand (issue early; independent of softmax):
        // lane holds d-row = t*32+ql, k = kc*16 + hi*8 + 0..7 (contiguous in Vt)
        const unsigned short* vp = Vt + (size_t)ql * 2048 + kb + hi * 8;
        bf16x8 va00 = *(const bf16x8*)(vp);
        bf16x8 va01 = *(const bf16x8*)(vp + 16);
        bf16x8 va10 = *(const bf16x8*)(vp + 32 * 2048);
        bf16x8 va11 = *(const bf16x8*)(vp + 32 * 2048 + 16);

        // ---- online softmax (q = lane column; k spread over 16 regs x 2 hi halves)
        float mx = s[0];
        #pragma unroll
        for (int r = 1; r < 16; ++r) mx = fmaxf(mx, s[r]);
        mx = fmaxf(mx, __shfl_xor(mx, 32));

        if (!__all(mx <= m + 8.0f)) {          // T13 defer-max
            float mn = fmaxf(m, mx);
            float corr = exp2f((m - mn) * LOG2E);
            m = mn;
            lsum *= corr;
            #pragma unroll
            for (int r = 0; r < 16; ++r) { o0[r] *= corr; o1[r] *= corr; }
        }

        float p[16];
        float rs = 0.f;
        #pragma unroll
        for (int r = 0; r < 16; ++r) {
            p[r] = exp2f((s[r] - m) * LOG2E);
            rs += p[r];
        }
        rs += __shfl_xor(rs, 32);
        lsum += rs;

        // ---- P relayout: C-layout -> B-operand layout (T12: cvt_pk + shfl_xor(32))
        uint4 pbw[2];
        #pragma unroll
        for (int kc = 0; kc < 2; ++kc) {
            const int pb0 = kc * 8;
            unsigned int x0, x1, x2, x3;
            asm("v_cvt_pk_bf16_f32 %0, %1, %2" : "=v"(x0) : "v"(p[pb0 + 0]), "v"(p[pb0 + 1]));
            asm("v_cvt_pk_bf16_f32 %0, %1, %2" : "=v"(x1) : "v"(p[pb0 + 2]), "v"(p[pb0 + 3]));
            asm("v_cvt_pk_bf16_f32 %0, %1, %2" : "=v"(x2) : "v"(p[pb0 + 4]), "v"(p[pb0 + 5]));
            asm("v_cvt_pk_bf16_f32 %0, %1, %2" : "=v"(x3) : "v"(p[pb0 + 6]), "v"(p[pb0 + 7]));
            unsigned int sx0 = (unsigned int)__shfl_xor((int)x0, 32);
            unsigned int sx1 = (unsigned int)__shfl_xor((int)x1, 32);
            unsigned int sx2 = (unsigned int)__shfl_xor((int)x2, 32);
            unsigned int sx3 = (unsigned int)__shfl_xor((int)x3, 32);
            pbw[kc].x = hi ? sx2 : x0;
            pbw[kc].y = hi ? sx3 : x1;
            pbw[kc].z = hi ? x2 : sx0;
            pbw[kc].w = hi ? x3 : sx1;
        }
        bf16x8 pB0 = __builtin_bit_cast(bf16x8, pbw[0]);
        bf16x8 pB1 = __builtin_bit_cast(bf16x8, pbw[1]);

        // ---- PV: O^T[t] += Vt_frag x P^T
        o0 = __builtin_amdgcn_mfma_f32_32x32x16_bf16(va00, pB0, o0, 0, 0, 0);
        o0 = __builtin_amdgcn_mfma_f32_32x32x16_bf16(va01, pB1, o0, 0, 0, 0);
        o1 = __builtin_amdgcn_mfma_f32_32x32x16_bf16(va10, pB0, o1, 0, 0, 0);
        o1 = __builtin_amdgcn_mfma_f32_32x32x16_bf16(va11, pB1, o1, 0, 0, 0);
    }

    // ---- epilogue: lane column q -> out[b][n=q0+ql][h*64 + d], d from reg pattern
    const int b = bh >> 4, h = bh & 15;
    const float inv = 1.0f / lsum;
    const int n = q0 + ql;
    unsigned short* obase = out + ((size_t)(b * 2048 + n)) * 1024 + h * 64;
    #pragma unroll
    for (int g = 0; g < 4; ++g) {
        int d0 = 8 * g + 4 * hi;       // regs 4g..4g+3 -> d = d0..d0+3
        ushort4 w0, w1;
        w0.x = f2bf(o0[4 * g + 0] * inv);
        w0.y = f2bf(o0[4 * g + 1] * inv);
        w0.z = f2bf(o0[4 * g + 2] * inv);
        w0.w = f2bf(o0[4 * g + 3] * inv);
        *(ushort4*)(obase + d0) = w0;
        w1.x = f2bf(o1[4 * g + 0] * inv);
        w1.y = f2bf(o1[4 * g + 1] * inv);
        w1.z = f2bf(o1[4 * g + 2] * inv);
        w1.w = f2bf(o1[4 * g + 3] * inv);
        *(ushort4*)(obase + 32 + d0) = w1;
    }
}

// ---------------- launch ----------------
extern "C" void kernel_launch(void* const* d_in, const int* in_sizes, int n_in,
                              void* d_out, int out_size, void* d_ws, size_t ws_size,
                              hipStream_t stream) {
    (void)in_sizes; (void)n_in; (void)out_size; (void)ws_size;
    const float* x     = (const float*)d_in[0];
    const float* w_qkv = (const float*)d_in[1];
    const float* b_qkv = (const float*)d_in[2];
    const float* w_out = (const float*)d_in[3];
    const float* b_out = (const float*)d_in[4];

    unsigned short* ws = (unsigned short*)d_ws;
    unsigned short* xb    = ws;
    unsigned short* wqkvb = ws + 8388608;
    unsigned short* woutb = ws + 11534336;
    unsigned short* qkvb  = ws + 12582912;

    cvt_kernel<<<dim3(2048), dim3(256), 0, stream>>>(x, xb, 8388608 / 4);
    cvt_kernel<<<dim3(1024), dim3(256), 0, stream>>>(w_qkv, wqkvb, 3145728 / 4);
    cvt_kernel<<<dim3(512),  dim3(256), 0, stream>>>(w_out, woutb, 1048576 / 4);

    gemm_bt<0><<<dim3(24, 64), dim3(256), 0, stream>>>(xb, wqkvb, b_qkv, (void*)qkvb, 8192, 3072, 1024);

    // attn overwrites xb (x is dead after the QKV GEMM)
    attn_kernel<<<dim3(16, 64), dim3(256), 0, stream>>>(qkvb, xb);

    gemm_bt<1><<<dim3(8, 64), dim3(256), 0, stream>>>(xb, woutb, b_out, d_out, 8192, 1024, 1024);
}

// Round 3
// 367.578 us; speedup vs baseline: 1.7701x; 1.0091x over previous
//
#include <hip/hip_runtime.h>

typedef __bf16 bf16x8 __attribute__((ext_vector_type(8)));
typedef float f32x4 __attribute__((ext_vector_type(4)));
typedef float f32x16 __attribute__((ext_vector_type(16)));
typedef unsigned int uint2v __attribute__((ext_vector_type(2)));

#define LOG2E 1.44269504088896340736f

#if __has_builtin(__builtin_amdgcn_exp2f)
#define EXP2(x) __builtin_amdgcn_exp2f(x)
#else
#define EXP2(x) exp2f(x)
#endif

static __device__ __forceinline__ unsigned short f2bf(float f) {
    unsigned int u = __builtin_bit_cast(unsigned int, f);
    u += 0x7fffu + ((u >> 16) & 1u);   // RNE
    return (unsigned short)(u >> 16);
}

// v_permlane32_swap_b32: a_hi <-> b_lo. After: a = {a_lo, b_lo}, b = {a_hi, b_hi}.
static __device__ __forceinline__ void plswap(unsigned int& a, unsigned int& b) {
#if __has_builtin(__builtin_amdgcn_permlane32_swap)
    uint2v r = __builtin_amdgcn_permlane32_swap(a, b, false, false);
    a = r.x; b = r.y;
#else
    asm("v_permlane32_swap_b32 %0, %1" : "+v"(a), "+v"(b));
#endif
}

static __device__ __forceinline__ float xhalf_max(float x) {
    unsigned int a = __builtin_bit_cast(unsigned int, x), b = a;
    plswap(a, b);
    return fmaxf(__builtin_bit_cast(float, a), __builtin_bit_cast(float, b));
}

static __device__ __forceinline__ float xhalf_add(float x) {
    unsigned int a = __builtin_bit_cast(unsigned int, x), b = a;
    plswap(a, b);
    return __builtin_bit_cast(float, a) + __builtin_bit_cast(float, b);
}

// ---------------- fp32 -> bf16 convert ----------------
__global__ void cvt_kernel(const float* __restrict__ in, unsigned short* __restrict__ out, int n4) {
    int i = blockIdx.x * blockDim.x + threadIdx.x;
    int stride = gridDim.x * blockDim.x;
    for (; i < n4; i += stride) {
        float4 v = reinterpret_cast<const float4*>(in)[i];
        ushort4 o;
        o.x = f2bf(v.x); o.y = f2bf(v.y); o.z = f2bf(v.z); o.w = f2bf(v.w);
        reinterpret_cast<ushort4*>(out)[i] = o;
    }
}

// ---------------- bf16 GEMM, C = A * B^T (+bias) ----------------
template <int MODE>
__global__ __launch_bounds__(256, 2) void gemm_bt(const unsigned short* __restrict__ A,
                                                  const unsigned short* __restrict__ B,
                                                  const float* __restrict__ bias,
                                                  void* __restrict__ Cout,
                                                  int M, int N, int K) {
    __shared__ unsigned short As[2][128 * 64];
    __shared__ unsigned short Bs[2][128 * 64];
    const int tid = threadIdx.x;
    const int w = tid >> 6, lane = tid & 63;
    const int wr = w >> 1, wc = w & 1;
    const int bm0 = blockIdx.y << 7, bn0 = blockIdx.x << 7;
    const int l15 = lane & 15, l4 = lane >> 4;

    const int srow = w * 8 + (lane >> 3);
    const int gch = (lane & 7) ^ (lane >> 3);

    f32x4 acc[4][4] = {};

    auto stage = [&](int buf, int kt) {
        const int k0 = kt << 6;
        #pragma unroll
        for (int i = 0; i < 4; ++i) {
            int row = i * 32 + srow;
            const unsigned short* ga = A + (size_t)(bm0 + row) * K + k0 + gch * 8;
            __builtin_amdgcn_global_load_lds(
                (const __attribute__((address_space(1))) void*)ga,
                (__attribute__((address_space(3))) void*)&As[buf][i * 2048 + w * 512],
                16, 0, 0);
            const unsigned short* gb = B + (size_t)(bn0 + row) * K + k0 + gch * 8;
            __builtin_amdgcn_global_load_lds(
                (const __attribute__((address_space(1))) void*)gb,
                (__attribute__((address_space(3))) void*)&Bs[buf][i * 2048 + w * 512],
                16, 0, 0);
        }
    };

    const int nk = K >> 6;
    stage(0, 0);
    __syncthreads();
    int buf = 0;
    for (int kt = 0; kt < nk; ++kt) {
        if (kt + 1 < nk) stage(buf ^ 1, kt + 1);
        const unsigned short* as = &As[buf][0];
        const unsigned short* bs = &Bs[buf][0];
        #pragma unroll
        for (int s = 0; s < 2; ++s) {
            bf16x8 af[4], bfr[4];
            #pragma unroll
            for (int t = 0; t < 4; ++t) {
                int rowa = wr * 64 + t * 16 + l15;
                int cha = (s * 4 + l4) ^ (rowa & 7);
                af[t] = *(const bf16x8*)&as[rowa * 64 + cha * 8];
                int rowb = wc * 64 + t * 16 + l15;
                int chb = (s * 4 + l4) ^ (rowb & 7);
                bfr[t] = *(const bf16x8*)&bs[rowb * 64 + chb * 8];
            }
            #pragma unroll
            for (int i = 0; i < 4; ++i)
                #pragma unroll
                for (int j = 0; j < 4; ++j)
                    acc[i][j] = __builtin_amdgcn_mfma_f32_16x16x32_bf16(af[i], bfr[j], acc[i][j], 0, 0, 0);
        }
        __syncthreads();
        buf ^= 1;
    }

    if (MODE == 0) {
        unsigned short* O = (unsigned short*)Cout;
        #pragma unroll
        for (int j = 0; j < 4; ++j) {
            int col = bn0 + wc * 64 + j * 16 + l15;
            float bv = bias[col];
            int which = col >> 10;
            int h = (col >> 6) & 15;
            int d = col & 63;
            #pragma unroll
            for (int i = 0; i < 4; ++i) {
                #pragma unroll
                for (int r = 0; r < 4; ++r) {
                    int row = bm0 + wr * 64 + i * 16 + l4 * 4 + r;
                    int b = row >> 11, n = row & 2047;
                    float v = acc[i][j][r] + bv;
                    size_t idx;
                    // Q scaled by 1/sqrt(64) * log2(e): softmax runs in log2 domain
                    if (which == 0) { v *= 0.125f * LOG2E; idx = ((size_t)((b * 16 + h) * 2048 + n)) * 64 + d; }
                    else if (which == 1) { idx = (size_t)8388608 + ((size_t)((b * 16 + h) * 2048 + n)) * 64 + d; }
                    else { idx = (size_t)16777216 + ((size_t)((b * 16 + h) * 64 + d)) * 2048 + n; }
                    O[idx] = f2bf(v);
                }
            }
        }
    } else {
        float* C = (float*)Cout;
        #pragma unroll
        for (int j = 0; j < 4; ++j) {
            int col = bn0 + wc * 64 + j * 16 + l15;
            float bv = bias[col];
            #pragma unroll
            for (int i = 0; i < 4; ++i) {
                #pragma unroll
                for (int r = 0; r < 4; ++r) {
                    int row = bm0 + wr * 64 + i * 16 + l4 * 4 + r;
                    C[(size_t)row * N + col] = acc[i][j][r] + bv;
                }
            }
        }
    }
}

// ---------------- flash attention v3: swapped 32x32, reg-prefetched, permlane, raw exp2 ----------------
__global__ __launch_bounds__(256, 3) void attn_kernel(const unsigned short* __restrict__ qkv,
                                                      unsigned short* __restrict__ out) {
    const int tid = threadIdx.x;
    const int w = tid >> 6, lane = tid & 63;
    const int ql = lane & 31;
    const int hi = lane >> 5;
    const int qt = blockIdx.x;       // 0..15
    const int bh = blockIdx.y;       // 0..63
    const size_t SEC = 8388608;

    const unsigned short* Q  = qkv + (size_t)bh * (2048 * 64);
    const unsigned short* Kp = qkv + SEC + (size_t)bh * (2048 * 64);
    const unsigned short* Vt = qkv + 2 * SEC + (size_t)bh * (64 * 2048);

    const int q0 = qt * 128 + w * 32;

    bf16x8 qb[4];
    #pragma unroll
    for (int c = 0; c < 4; ++c)
        qb[c] = *(const bf16x8*)&Q[(size_t)(q0 + ql) * 64 + c * 16 + hi * 8];

    f32x16 o0 = {}, o1 = {};
    float m = -1e30f, lsum = 0.f;

    const unsigned short* kbase = Kp + (size_t)ql * 64 + hi * 8;
    const unsigned short* vbase = Vt + (size_t)ql * 2048 + hi * 8;

    bf16x8 kA[4], kB[4];
    #pragma unroll
    for (int c = 0; c < 4; ++c) kA[c] = *(const bf16x8*)(kbase + c * 16);

    auto iter = [&](bf16x8 (&kc)[4], bf16x8 (&kn)[4], int kb, int kbn) {
        // V for current tile (used late -> in-iteration latency cover)
        const unsigned short* vp = vbase + kb;
        bf16x8 va00 = *(const bf16x8*)(vp);
        bf16x8 va01 = *(const bf16x8*)(vp + 16);
        bf16x8 va10 = *(const bf16x8*)(vp + 32 * 2048);
        bf16x8 va11 = *(const bf16x8*)(vp + 32 * 2048 + 16);

        // S^T = K x Q (lane column = q)
        f32x16 s = {};
        s = __builtin_amdgcn_mfma_f32_32x32x16_bf16(kc[0], qb[0], s, 0, 0, 0);
        s = __builtin_amdgcn_mfma_f32_32x32x16_bf16(kc[1], qb[1], s, 0, 0, 0);
        s = __builtin_amdgcn_mfma_f32_32x32x16_bf16(kc[2], qb[2], s, 0, 0, 0);
        s = __builtin_amdgcn_mfma_f32_32x32x16_bf16(kc[3], qb[3], s, 0, 0, 0);

        // prefetch NEXT K tile into the other buffer (consumed next iteration)
        const unsigned short* kp2 = kbase + (size_t)kbn * 64;
        kn[0] = *(const bf16x8*)(kp2);
        kn[1] = *(const bf16x8*)(kp2 + 16);
        kn[2] = *(const bf16x8*)(kp2 + 32);
        kn[3] = *(const bf16x8*)(kp2 + 48);

        // row max: max3-shaped tree (depth ~3) + one permlane cross-half
        float t0 = fmaxf(fmaxf(s[0], s[1]), s[2]);
        float t1 = fmaxf(fmaxf(s[3], s[4]), s[5]);
        float t2 = fmaxf(fmaxf(s[6], s[7]), s[8]);
        float t3 = fmaxf(fmaxf(s[9], s[10]), s[11]);
        float t4 = fmaxf(fmaxf(s[12], s[13]), s[14]);
        float mx = fmaxf(fmaxf(fmaxf(t0, t1), t2), fmaxf(fmaxf(t3, t4), s[15]));
        mx = xhalf_max(mx);

        if (!__all(mx <= m + 8.0f)) {          // T13 defer-max (log2 domain)
            float mn = fmaxf(m, mx);
            float corr = EXP2(m - mn);
            m = mn;
            lsum *= corr;
            #pragma unroll
            for (int r = 0; r < 16; ++r) { o0[r] *= corr; o1[r] *= corr; }
        }

        float p[16];
        #pragma unroll
        for (int r = 0; r < 16; ++r) p[r] = EXP2(s[r] - m);
        float u0 = (p[0] + p[1]) + (p[2] + p[3]);
        float u1 = (p[4] + p[5]) + (p[6] + p[7]);
        float u2 = (p[8] + p[9]) + (p[10] + p[11]);
        float u3 = (p[12] + p[13]) + (p[14] + p[15]);
        float rs = (u0 + u1) + (u2 + u3);
        rs = xhalf_add(rs);
        lsum += rs;

        // P relayout C->B in-register: cvt_pk pairs + permlane32_swap (T12)
        bf16x8 pB[2];
        #pragma unroll
        for (int g = 0; g < 2; ++g) {
            unsigned int x0, x1, x2, x3;
            asm("v_cvt_pk_bf16_f32 %0, %1, %2" : "=v"(x0) : "v"(p[8*g + 0]), "v"(p[8*g + 1]));
            asm("v_cvt_pk_bf16_f32 %0, %1, %2" : "=v"(x1) : "v"(p[8*g + 2]), "v"(p[8*g + 3]));
            asm("v_cvt_pk_bf16_f32 %0, %1, %2" : "=v"(x2) : "v"(p[8*g + 4]), "v"(p[8*g + 5]));
            asm("v_cvt_pk_bf16_f32 %0, %1, %2" : "=v"(x3) : "v"(p[8*g + 6]), "v"(p[8*g + 7]));
            plswap(x0, x2);   // -> word0, word2
            plswap(x1, x3);   // -> word1, word3
            uint4 wds;
            wds.x = x0; wds.y = x1; wds.z = x2; wds.w = x3;
            pB[g] = __builtin_bit_cast(bf16x8, wds);
        }

        // O^T += Vt x P^T
        o0 = __builtin_amdgcn_mfma_f32_32x32x16_bf16(va00, pB[0], o0, 0, 0, 0);
        o0 = __builtin_amdgcn_mfma_f32_32x32x16_bf16(va01, pB[1], o0, 0, 0, 0);
        o1 = __builtin_amdgcn_mfma_f32_32x32x16_bf16(va10, pB[0], o1, 0, 0, 0);
        o1 = __builtin_amdgcn_mfma_f32_32x32x16_bf16(va11, pB[1], o1, 0, 0, 0);
    };

    for (int t = 0; t < 64; t += 2) {
        iter(kA, kB, t * 32, (t + 1) * 32);
        iter(kB, kA, (t + 1) * 32, ((t + 2) & 63) * 32);   // wrap on last (unused)
    }

    // epilogue: lane column q -> out[b][n][h*64+d]
    const int b = bh >> 4, h = bh & 15;
    const float inv = 1.0f / lsum;
    const int n = q0 + ql;
    unsigned short* obase = out + ((size_t)(b * 2048 + n)) * 1024 + h * 64;
    #pragma unroll
    for (int g = 0; g < 4; ++g) {
        int d0 = 8 * g + 4 * hi;
        ushort4 w0, w1;
        w0.x = f2bf(o0[4 * g + 0] * inv);
        w0.y = f2bf(o0[4 * g + 1] * inv);
        w0.z = f2bf(o0[4 * g + 2] * inv);
        w0.w = f2bf(o0[4 * g + 3] * inv);
        *(ushort4*)(obase + d0) = w0;
        w1.x = f2bf(o1[4 * g + 0] * inv);
        w1.y = f2bf(o1[4 * g + 1] * inv);
        w1.z = f2bf(o1[4 * g + 2] * inv);
        w1.w = f2bf(o1[4 * g + 3] * inv);
        *(ushort4*)(obase + 32 + d0) = w1;
    }
}

// ---------------- launch ----------------
extern "C" void kernel_launch(void* const* d_in, const int* in_sizes, int n_in,
                              void* d_out, int out_size, void* d_ws, size_t ws_size,
                              hipStream_t stream) {
    (void)in_sizes; (void)n_in; (void)out_size; (void)ws_size;
    const float* x     = (const float*)d_in[0];
    const float* w_qkv = (const float*)d_in[1];
    const float* b_qkv = (const float*)d_in[2];
    const float* w_out = (const float*)d_in[3];
    const float* b_out = (const float*)d_in[4];

    unsigned short* ws = (unsigned short*)d_ws;
    unsigned short* xb    = ws;
    unsigned short* wqkvb = ws + 8388608;
    unsigned short* woutb = ws + 11534336;
    unsigned short* qkvb  = ws + 12582912;

    cvt_kernel<<<dim3(2048), dim3(256), 0, stream>>>(x, xb, 8388608 / 4);
    cvt_kernel<<<dim3(1024), dim3(256), 0, stream>>>(w_qkv, wqkvb, 3145728 / 4);
    cvt_kernel<<<dim3(512),  dim3(256), 0, stream>>>(w_out, woutb, 1048576 / 4);

    gemm_bt<0><<<dim3(24, 64), dim3(256), 0, stream>>>(xb, wqkvb, b_qkv, (void*)qkvb, 8192, 3072, 1024);

    attn_kernel<<<dim3(16, 64), dim3(256), 0, stream>>>(qkvb, xb);

    gemm_bt<1><<<dim3(8, 64), dim3(256), 0, stream>>>(xb, woutb, b_out, d_out, 8192, 1024, 1024);
}